// Round 2
// baseline (961.645 us; speedup 1.0000x reference)
//
#include <hip/hip_runtime.h>

// Trilinear sampling of tsdf/weights volumes at M = B*H*N points, D=256.
// Outputs concatenated flat in d_out as float32:
//   [0,        M)   fusion_values
//   [M,      25M)   indices  (M,8,3) -- integer-valued floats
//   [25M,    33M)   weights  (M,8)
//   [33M,    34M)   fusion_weights
//
// Strategy: random points => gathers have no locality (R1: FETCH 1.4 GB vs
// ~170 MB useful). Counting-sort points by 8^3-voxel bucket (32^3 buckets),
// run the volume gathers in sorted order (L1/L2-resident working set per
// bucket), scatter only 8 B/point (fv/fw). Indices/weights need no volume
// access and are written coalesced in natural order.

#define NBUCK 32768  // 32^3 buckets of 8^3 voxels

__device__ __forceinline__ int bucket_of(int bx, int by, int bz) {
    const int qx = min(max(bx, 0), 255) >> 3;
    const int qy = min(max(by, 0), 255) >> 3;
    const int qz = min(max(bz, 0), 255) >> 3;
    return (qx << 10) | (qy << 5) | qz;
}

// ---- K1: natural order: indices + weights (coalesced writes) + histogram ----
__global__ __launch_bounds__(256) void idxw_hist_kernel(
    const float* __restrict__ points, float* __restrict__ out,
    int* __restrict__ hist, int M)
{
    const int m = blockIdx.x * 256 + threadIdx.x;
    if (m >= M) return;
    const size_t p3 = 3ull * (size_t)m;
    const float px = points[p3 + 0], py = points[p3 + 1], pz = points[p3 + 2];

    const float fx = floorf(px), fy = floorf(py), fz = floorf(pz);
    const int bx = (int)fx, by = (int)fy, bz = (int)fz;
    const float dxc = fx + 0.5f - px, dyc = fy + 0.5f - py, dzc = fz + 0.5f - pz;
    const int nx = (dxc > 0.f) ? 1 : ((dxc < 0.f) ? -1 : 0);
    const int ny = (dyc > 0.f) ? 1 : ((dyc < 0.f) ? -1 : 0);
    const int nz = (dzc > 0.f) ? 1 : ((dzc < 0.f) ? -1 : 0);
    const float ax = fabsf(dxc), ay = fabsf(dyc), az = fabsf(dzc);
    const float axi = 1.f - ax, ayi = 1.f - ay, azi = 1.f - az;

    float idxf[24], wts[8];
#pragma unroll
    for (int c = 0; c < 8; ++c) {
        const int ox = (c >> 2) & 1, oy = (c >> 1) & 1, oz = c & 1;
        idxf[c * 3 + 0] = (float)(bx + (ox ? nx : 0));
        idxf[c * 3 + 1] = (float)(by + (oy ? ny : 0));
        idxf[c * 3 + 2] = (float)(bz + (oz ? nz : 0));
        wts[c] = (ox ? ax : axi) * (oy ? ay : ayi) * (oz ? az : azi);
    }

    const size_t Ms = (size_t)M;
    float4* __restrict__ oi = reinterpret_cast<float4*>(out + Ms + (size_t)m * 24);
    const float4* ii = reinterpret_cast<const float4*>(idxf);
#pragma unroll
    for (int i = 0; i < 6; ++i) oi[i] = ii[i];
    float4* __restrict__ ow = reinterpret_cast<float4*>(out + 25 * Ms + (size_t)m * 8);
    const float4* wi = reinterpret_cast<const float4*>(wts);
    ow[0] = wi[0];
    ow[1] = wi[1];

    atomicAdd(&hist[bucket_of(bx, by, bz)], 1);
}

// ---- K2: exclusive prefix sum over NBUCK counters (one block) ----
__global__ __launch_bounds__(1024) void scan_kernel(
    const int* __restrict__ hist, int* __restrict__ offs)
{
    __shared__ int partial[1024];
    const int t = threadIdx.x;
    const int base = t * 32;
    int loc[32];
    int s = 0;
#pragma unroll
    for (int i = 0; i < 32; ++i) { loc[i] = s; s += hist[base + i]; }
    partial[t] = s;
    __syncthreads();
    // Hillis-Steele inclusive scan over 1024 partials
    for (int off = 1; off < 1024; off <<= 1) {
        int v = (t >= off) ? partial[t - off] : 0;
        __syncthreads();
        partial[t] += v;
        __syncthreads();
    }
    const int chunk_off = (t == 0) ? 0 : partial[t - 1];
#pragma unroll
    for (int i = 0; i < 32; ++i) offs[base + i] = chunk_off + loc[i];
}

// ---- K3: scatter point coords (+orig id) into bucket-sorted order ----
__global__ __launch_bounds__(256) void scatter_kernel(
    const float* __restrict__ points, int* __restrict__ offs,
    float4* __restrict__ sorted, int M)
{
    const int m = blockIdx.x * 256 + threadIdx.x;
    if (m >= M) return;
    const size_t p3 = 3ull * (size_t)m;
    const float px = points[p3 + 0], py = points[p3 + 1], pz = points[p3 + 2];
    const int b = bucket_of((int)floorf(px), (int)floorf(py), (int)floorf(pz));
    const int pos = atomicAdd(&offs[b], 1);
    sorted[pos] = make_float4(px, py, pz, __uint_as_float((unsigned)m));
}

// ---- K4: sorted-order gather: fv/fw only, scattered 8 B/point write ----
__global__ __launch_bounds__(256) void gather_kernel(
    const float4* __restrict__ sorted,
    const float* __restrict__ tsdf, const float* __restrict__ wvol,
    float* __restrict__ out, int M)
{
    const int m = blockIdx.x * 256 + threadIdx.x;
    if (m >= M) return;
    const float4 s = sorted[m];
    const float px = s.x, py = s.y, pz = s.z;
    const unsigned orig = __float_as_uint(s.w);

    const float fx = floorf(px), fy = floorf(py), fz = floorf(pz);
    const int bx = (int)fx, by = (int)fy, bz = (int)fz;
    const float dxc = fx + 0.5f - px, dyc = fy + 0.5f - py, dzc = fz + 0.5f - pz;
    const int nx = (dxc > 0.f) ? 1 : ((dxc < 0.f) ? -1 : 0);
    const int ny = (dyc > 0.f) ? 1 : ((dyc < 0.f) ? -1 : 0);
    const int nz = (dzc > 0.f) ? 1 : ((dzc < 0.f) ? -1 : 0);
    const float ax = fabsf(dxc), ay = fabsf(dyc), az = fabsf(dzc);
    const float axi = 1.f - ax, ayi = 1.f - ay, azi = 1.f - az;

    float fv = 0.f, fw = 0.f;
#pragma unroll
    for (int c = 0; c < 8; ++c) {
        const int ox = (c >> 2) & 1, oy = (c >> 1) & 1, oz = c & 1;
        const int cx = bx + (ox ? nx : 0);
        const int cy = by + (oy ? ny : 0);
        const int cz = bz + (oz ? nz : 0);
        const float w = (ox ? ax : axi) * (oy ? ay : ayi) * (oz ? az : azi);
        const bool valid = ((unsigned)cx < 256u) & ((unsigned)cy < 256u) & ((unsigned)cz < 256u);
        const int flat = (min(max(cx, 0), 255) << 16) |
                         (min(max(cy, 0), 255) << 8)  |
                          min(max(cz, 0), 255);
        const float vm = valid ? 1.f : 0.f;
        fv += tsdf[flat] * vm * w;
        fw += wvol[flat] * vm * w;
    }

    const size_t Ms = (size_t)M;
    out[orig] = fv;
    out[33 * Ms + orig] = fw;
}

// ---- fallback: round-1 monolithic kernel (used if ws too small) ----
__global__ __launch_bounds__(256) void extractor_mono_kernel(
    const float* __restrict__ points,
    const float* __restrict__ tsdf, const float* __restrict__ wvol,
    float* __restrict__ out, int M)
{
    const int m = blockIdx.x * 256 + threadIdx.x;
    if (m >= M) return;
    const size_t p3 = 3ull * (size_t)m;
    const float px = points[p3 + 0], py = points[p3 + 1], pz = points[p3 + 2];
    const float fx = floorf(px), fy = floorf(py), fz = floorf(pz);
    const int bx = (int)fx, by = (int)fy, bz = (int)fz;
    const float dxc = fx + 0.5f - px, dyc = fy + 0.5f - py, dzc = fz + 0.5f - pz;
    const int nx = (dxc > 0.f) ? 1 : ((dxc < 0.f) ? -1 : 0);
    const int ny = (dyc > 0.f) ? 1 : ((dyc < 0.f) ? -1 : 0);
    const int nz = (dzc > 0.f) ? 1 : ((dzc < 0.f) ? -1 : 0);
    const float ax = fabsf(dxc), ay = fabsf(dyc), az = fabsf(dzc);
    const float axi = 1.f - ax, ayi = 1.f - ay, azi = 1.f - az;
    float fv = 0.f, fw = 0.f;
    float idxf[24], wts[8];
#pragma unroll
    for (int c = 0; c < 8; ++c) {
        const int ox = (c >> 2) & 1, oy = (c >> 1) & 1, oz = c & 1;
        const int cx = bx + (ox ? nx : 0);
        const int cy = by + (oy ? ny : 0);
        const int cz = bz + (oz ? nz : 0);
        const float w = (ox ? ax : axi) * (oy ? ay : ayi) * (oz ? az : azi);
        const bool valid = ((unsigned)cx < 256u) & ((unsigned)cy < 256u) & ((unsigned)cz < 256u);
        const int flat = (min(max(cx, 0), 255) << 16) |
                         (min(max(cy, 0), 255) << 8)  |
                          min(max(cz, 0), 255);
        const float vm = valid ? 1.f : 0.f;
        fv += tsdf[flat] * vm * w;
        fw += wvol[flat] * vm * w;
        idxf[c * 3 + 0] = (float)cx;
        idxf[c * 3 + 1] = (float)cy;
        idxf[c * 3 + 2] = (float)cz;
        wts[c] = w;
    }
    const size_t Ms = (size_t)M;
    out[m] = fv;
    out[33 * Ms + m] = fw;
    float4* oi = reinterpret_cast<float4*>(out + Ms + (size_t)m * 24);
    const float4* ii = reinterpret_cast<const float4*>(idxf);
#pragma unroll
    for (int i = 0; i < 6; ++i) oi[i] = ii[i];
    float4* ow = reinterpret_cast<float4*>(out + 25 * Ms + (size_t)m * 8);
    const float4* wi = reinterpret_cast<const float4*>(wts);
    ow[0] = wi[0];
    ow[1] = wi[1];
}

extern "C" void kernel_launch(void* const* d_in, const int* in_sizes, int n_in,
                              void* d_out, int out_size, void* d_ws, size_t ws_size,
                              hipStream_t stream) {
    const float* points = (const float*)d_in[0];
    const float* tsdf   = (const float*)d_in[1];
    const float* wvol   = (const float*)d_in[2];
    float* out = (float*)d_out;

    const int M = in_sizes[0] / 3;
    const int blocks = (M + 255) / 256;

    // ws layout: [hist NBUCK ints][offs NBUCK ints][sorted_pts M float4]
    const size_t need = (size_t)NBUCK * 4 * 2 + (size_t)M * 16;
    if (ws_size < need) {
        extractor_mono_kernel<<<blocks, 256, 0, stream>>>(points, tsdf, wvol, out, M);
        return;
    }

    int* hist = (int*)d_ws;
    int* offs = hist + NBUCK;
    float4* sorted = (float4*)(offs + NBUCK);

    hipMemsetAsync(hist, 0, (size_t)NBUCK * 4, stream);
    idxw_hist_kernel<<<blocks, 256, 0, stream>>>(points, out, hist, M);
    scan_kernel<<<1, 1024, 0, stream>>>(hist, offs);
    scatter_kernel<<<blocks, 256, 0, stream>>>(points, offs, sorted, M);
    gather_kernel<<<blocks, 256, 0, stream>>>(sorted, tsdf, wvol, out, M);
}